// Round 1
// baseline (1552.661 us; speedup 1.0000x reference)
//
#include <hip/hip_runtime.h>
#include <math.h>

#define F_IN 128
#define HID 64
#define NCLS 32
#define NEG 0.2f

// ---- float <-> order-preserving uint (for atomicMax on floats) ----
__device__ __forceinline__ unsigned f2ord(float f) {
    unsigned u = __float_as_uint(f);
    return (u & 0x80000000u) ? ~u : (u | 0x80000000u);
}
__device__ __forceinline__ float ord2f(unsigned k) {
    unsigned u = (k & 0x80000000u) ? (k & 0x7fffffffu) : ~k;
    return __uint_as_float(u);
}
// f2ord(-inf) = ~0xFF800000 = 0x007FFFFF
#define ORD_NEG_INF 0x007FFFFFu

// ---- init: acc[n*C+c] = bias[c]; mkey = -inf key; s = 0 ----
template <int C>
__global__ __launch_bounds__(256) void initK(float* __restrict__ acc,
                                             const float* __restrict__ bias,
                                             unsigned* __restrict__ mkey,
                                             float* __restrict__ s, int N) {
    int i = blockIdx.x * 256 + threadIdx.x;
    if (i < N * C) acc[i] = bias[i & (C - 1)];
    if (i < N) { mkey[i] = ORD_NEG_INF; s[i] = 0.f; }
}

// ---- layer-1 transform: xl = x@Wl+bl, xr = x@Wr+br  (K=128, C=64) ----
__global__ __launch_bounds__(256) void transform1(const float* __restrict__ x,
                                                  const float* __restrict__ Wl,
                                                  const float* __restrict__ bl,
                                                  const float* __restrict__ Wr,
                                                  const float* __restrict__ br,
                                                  float* __restrict__ xl,
                                                  float* __restrict__ xr, int N) {
    __shared__ float sx[4][F_IN];
    int w = threadIdx.x >> 6;    // wave in block -> node slot
    int lane = threadIdx.x & 63; // output channel
    int n = blockIdx.x * 4 + w;
    int n0 = n < N ? n : N - 1;
    sx[w][lane]      = x[(size_t)n0 * F_IN + lane];
    sx[w][lane + 64] = x[(size_t)n0 * F_IN + 64 + lane];
    __syncthreads();
    float al = bl[lane], ar = br[lane];
#pragma unroll
    for (int k = 0; k < F_IN; k++) {
        float xv = sx[w][k];
        al = fmaf(xv, Wl[k * HID + lane], al);
        ar = fmaf(xv, Wr[k * HID + lane], ar);
    }
    if (n < N) {
        xl[(size_t)n * HID + lane] = al;
        xr[(size_t)n * HID + lane] = ar;
    }
}

// ---- layer-2 transform: xl = relu(h)@Wl+bl, xr = relu(h)@Wr+br (K=64, C=32) ----
__global__ __launch_bounds__(256) void transform2(const float* __restrict__ h,
                                                  const float* __restrict__ Wl,
                                                  const float* __restrict__ bl,
                                                  const float* __restrict__ Wr,
                                                  const float* __restrict__ br,
                                                  float* __restrict__ xl,
                                                  float* __restrict__ xr, int N) {
    __shared__ float sh[8][HID];
    int t = threadIdx.x;
    int nb = blockIdx.x * 8;
#pragma unroll
    for (int j = 0; j < 2; j++) {
        int idx = t + j * 256;
        int nn = idx >> 6, kk = idx & 63;
        int gn = nb + nn; if (gn >= N) gn = N - 1;
        float v = h[(size_t)gn * HID + kk];
        sh[nn][kk] = v > 0.f ? v : 0.f;   // fused ReLU
    }
    __syncthreads();
    int slot = t >> 5, c = t & 31;
    int gn = nb + slot;
    float al = bl[c], ar = br[c];
#pragma unroll
    for (int k = 0; k < HID; k++) {
        float xv = sh[slot][k];
        al = fmaf(xv, Wl[k * NCLS + c], al);
        ar = fmaf(xv, Wr[k * NCLS + c], ar);
    }
    if (gn < N) {
        xl[(size_t)gn * NCLS + c] = al;
        xr[(size_t)gn * NCLS + c] = ar;
    }
}

// ---- per-edge logit + segment max.  C lanes per edge (C=64 or 32). ----
template <int C>
__global__ __launch_bounds__(256) void logitK(const float* __restrict__ xl,
                                              const float* __restrict__ xr,
                                              const float* __restrict__ att,
                                              const int* __restrict__ ei,
                                              int Eorig, int Etot,
                                              float* __restrict__ e,
                                              unsigned* __restrict__ mkey) {
    const int EP = 256 / C;
    int sub = threadIdx.x / C;
    int lane = threadIdx.x & (C - 1);
    int edge = blockIdx.x * EP + sub;
    if (edge >= Etot) return;
    int src, dst;
    if (edge < Eorig) { src = ei[edge]; dst = ei[Eorig + edge]; }
    else              { src = dst = edge - Eorig; }
    float v = xl[(size_t)src * C + lane] + xr[(size_t)dst * C + lane];
    v = v > 0.f ? v : NEG * v;           // leaky_relu
    float p = v * att[lane];
#pragma unroll
    for (int o = C / 2; o > 0; o >>= 1) p += __shfl_xor(p, o, 64);
    if (lane == 0) {
        e[edge] = p;
        atomicMax(&mkey[dst], f2ord(p));
    }
}

// ---- per-edge exp + segment sum (scalar, thread-per-edge) ----
__global__ __launch_bounds__(256) void expsum(float* __restrict__ e,
                                              const unsigned* __restrict__ mkey,
                                              float* __restrict__ s,
                                              const int* __restrict__ ei,
                                              int Eorig, int Etot) {
    int edge = blockIdx.x * 256 + threadIdx.x;
    if (edge >= Etot) return;
    int dst = edge < Eorig ? ei[Eorig + edge] : edge - Eorig;
    float m = ord2f(mkey[dst]);
    float ex = __expf(e[edge] - m);
    e[edge] = ex;
    atomicAdd(&s[dst], ex);
}

// ---- per-edge weighted aggregation: out[dst] += alpha * xl[src] ----
template <int C>
__global__ __launch_bounds__(256) void aggK(const float* __restrict__ xl,
                                            const float* __restrict__ e,
                                            const float* __restrict__ s,
                                            const int* __restrict__ ei,
                                            int Eorig, int Etot,
                                            float* __restrict__ out) {
    const int EP = 256 / C;
    int sub = threadIdx.x / C;
    int lane = threadIdx.x & (C - 1);
    int edge = blockIdx.x * EP + sub;
    if (edge >= Etot) return;
    int src, dst;
    if (edge < Eorig) { src = ei[edge]; dst = ei[Eorig + edge]; }
    else              { src = dst = edge - Eorig; }
    float alpha = e[edge] / (s[dst] + 1e-16f);
    atomicAdd(&out[(size_t)dst * C + lane], alpha * xl[(size_t)src * C + lane]);
}

extern "C" void kernel_launch(void* const* d_in, const int* in_sizes, int n_in,
                              void* d_out, int out_size, void* d_ws, size_t ws_size,
                              hipStream_t stream) {
    const float* x     = (const float*)d_in[0];
    const int*   ei    = (const int*)d_in[1];
    const float* W1l   = (const float*)d_in[2];
    const float* b1l   = (const float*)d_in[3];
    const float* W1r   = (const float*)d_in[4];
    const float* b1r   = (const float*)d_in[5];
    const float* att1  = (const float*)d_in[6];
    const float* bias1 = (const float*)d_in[7];
    const float* W2l   = (const float*)d_in[8];
    const float* b2l   = (const float*)d_in[9];
    const float* W2r   = (const float*)d_in[10];
    const float* b2r   = (const float*)d_in[11];
    const float* att2  = (const float*)d_in[12];
    const float* bias2 = (const float*)d_in[13];
    float* out = (float*)d_out;

    int N     = in_sizes[0] / F_IN;   // 100000
    int Eorig = in_sizes[1] / 2;      // 1600000
    int Etot  = Eorig + N;            // with self-loops

    // workspace carve-up (256B aligned)
    char* p = (char*)d_ws;
    auto alloc = [&](size_t bytes) { void* r = (void*)p; p += (bytes + 255) & ~(size_t)255; return r; };
    float*    xl1  = (float*)alloc((size_t)N * HID * 4);
    float*    xr1  = (float*)alloc((size_t)N * HID * 4);
    float*    h    = (float*)alloc((size_t)N * HID * 4);
    float*    xl2  = (float*)alloc((size_t)N * NCLS * 4);
    float*    xr2  = (float*)alloc((size_t)N * NCLS * 4);
    float*    e    = (float*)alloc((size_t)Etot * 4);
    float*    s    = (float*)alloc((size_t)N * 4);
    unsigned* mkey = (unsigned*)alloc((size_t)N * 4);

    // ---------------- layer 1 ----------------
    transform1<<<(N + 3) / 4, 256, 0, stream>>>(x, W1l, b1l, W1r, b1r, xl1, xr1, N);
    initK<HID><<<(N * HID + 255) / 256, 256, 0, stream>>>(h, bias1, mkey, s, N);
    logitK<HID><<<(Etot + 3) / 4, 256, 0, stream>>>(xl1, xr1, att1, ei, Eorig, Etot, e, mkey);
    expsum<<<(Etot + 255) / 256, 256, 0, stream>>>(e, mkey, s, ei, Eorig, Etot);
    aggK<HID><<<(Etot + 3) / 4, 256, 0, stream>>>(xl1, e, s, ei, Eorig, Etot, h);

    // ---------------- layer 2 ----------------
    transform2<<<(N + 7) / 8, 256, 0, stream>>>(h, W2l, b2l, W2r, b2r, xl2, xr2, N);
    initK<NCLS><<<(N * HID + 255) / 256, 256, 0, stream>>>(out, bias2, mkey, s, N);
    logitK<NCLS><<<(Etot + 7) / 8, 256, 0, stream>>>(xl2, xr2, att2, ei, Eorig, Etot, e, mkey);
    expsum<<<(Etot + 255) / 256, 256, 0, stream>>>(e, mkey, s, ei, Eorig, Etot);
    aggK<NCLS><<<(Etot + 7) / 8, 256, 0, stream>>>(xl2, e, s, ei, Eorig, Etot, out);
}

// Round 3
// 835.414 us; speedup vs baseline: 1.8586x; 1.8586x over previous
//
#include <hip/hip_runtime.h>
#include <math.h>

#define F_IN 128
#define HID 64
#define NCLS 32
#define NEG 0.2f

// =====================  CSR build  =====================

__global__ __launch_bounds__(256) void zeroK(int* __restrict__ cnt,
                                             int* __restrict__ cursor, int N) {
    int i = blockIdx.x * 256 + threadIdx.x;
    if (i < N) { cnt[i] = 0; cursor[i] = 0; }
}

__global__ __launch_bounds__(256) void histK(const int* __restrict__ ei,
                                             int Eorig, int Etot,
                                             int* __restrict__ cnt) {
    int edge = blockIdx.x * 256 + threadIdx.x;
    if (edge >= Etot) return;
    int dst = edge < Eorig ? ei[Eorig + edge] : edge - Eorig;
    atomicAdd(&cnt[dst], 1);
}

// pass A: per-block (1024 elems) exclusive scan; block totals to bsum
__global__ __launch_bounds__(256) void scanLocal(const int* __restrict__ cnt,
                                                 int* __restrict__ rowstart,
                                                 int* __restrict__ bsum, int N) {
    __shared__ int sd[256];
    int t = threadIdx.x;
    int base = blockIdx.x * 1024;
    int v[4], tsum = 0;
#pragma unroll
    for (int j = 0; j < 4; j++) {
        int idx = base + t * 4 + j;
        v[j] = idx < N ? cnt[idx] : 0;
        tsum += v[j];
    }
    sd[t] = tsum;
    __syncthreads();
    // Hillis-Steele inclusive scan over 256 thread sums
    for (int off = 1; off < 256; off <<= 1) {
        int x = (t >= off) ? sd[t - off] : 0;
        __syncthreads();
        sd[t] += x;
        __syncthreads();
    }
    int run = sd[t] - tsum;  // exclusive prefix for this thread
#pragma unroll
    for (int j = 0; j < 4; j++) {
        int idx = base + t * 4 + j;
        if (idx < N) rowstart[idx] = run;
        run += v[j];
    }
    if (t == 255) bsum[blockIdx.x] = sd[255];
}

// pass B: single block exclusive-scans the block sums (nb <= 256)
__global__ __launch_bounds__(256) void scanBsum(int* __restrict__ bsum, int nb) {
    __shared__ int sd[256];
    int t = threadIdx.x;
    int own = t < nb ? bsum[t] : 0;
    sd[t] = own;
    __syncthreads();
    for (int off = 1; off < 256; off <<= 1) {
        int x = (t >= off) ? sd[t - off] : 0;
        __syncthreads();
        sd[t] += x;
        __syncthreads();
    }
    if (t < nb) bsum[t] = sd[t] - own;
}

// pass C: add block offsets
__global__ __launch_bounds__(256) void scanAdd(int* __restrict__ rowstart,
                                               const int* __restrict__ bsum, int N) {
    int i = blockIdx.x * 256 + threadIdx.x;
    if (i < N) rowstart[i] += bsum[i >> 10];
}

__global__ __launch_bounds__(256) void scatterK(const int* __restrict__ ei,
                                                int Eorig, int Etot,
                                                const int* __restrict__ rowstart,
                                                int* __restrict__ cursor,
                                                int* __restrict__ srclist) {
    int edge = blockIdx.x * 256 + threadIdx.x;
    if (edge >= Etot) return;
    int src, dst;
    if (edge < Eorig) { src = ei[edge]; dst = ei[Eorig + edge]; }
    else              { src = dst = edge - Eorig; }
    int pos = atomicAdd(&cursor[dst], 1);
    srclist[rowstart[dst] + pos] = src;
}

// =====================  dense transforms  =====================

__global__ __launch_bounds__(256) void transform1(const float* __restrict__ x,
                                                  const float* __restrict__ Wl,
                                                  const float* __restrict__ bl,
                                                  const float* __restrict__ Wr,
                                                  const float* __restrict__ br,
                                                  float* __restrict__ xl,
                                                  float* __restrict__ xr, int N) {
    __shared__ float sx[4][F_IN];
    int w = threadIdx.x >> 6;
    int lane = threadIdx.x & 63;
    int n = blockIdx.x * 4 + w;
    int n0 = n < N ? n : N - 1;
    sx[w][lane]      = x[(size_t)n0 * F_IN + lane];
    sx[w][lane + 64] = x[(size_t)n0 * F_IN + 64 + lane];
    __syncthreads();
    float al = bl[lane], ar = br[lane];
#pragma unroll
    for (int k = 0; k < F_IN; k++) {
        float xv = sx[w][k];
        al = fmaf(xv, Wl[k * HID + lane], al);
        ar = fmaf(xv, Wr[k * HID + lane], ar);
    }
    if (n < N) {
        xl[(size_t)n * HID + lane] = al;
        xr[(size_t)n * HID + lane] = ar;
    }
}

__global__ __launch_bounds__(256) void transform2(const float* __restrict__ h,
                                                  const float* __restrict__ Wl,
                                                  const float* __restrict__ bl,
                                                  const float* __restrict__ Wr,
                                                  const float* __restrict__ br,
                                                  float* __restrict__ xl,
                                                  float* __restrict__ xr, int N) {
    __shared__ float sh[8][HID];
    int t = threadIdx.x;
    int nb = blockIdx.x * 8;
#pragma unroll
    for (int j = 0; j < 2; j++) {
        int idx = t + j * 256;
        int nn = idx >> 6, kk = idx & 63;
        int gn = nb + nn; if (gn >= N) gn = N - 1;
        float v = h[(size_t)gn * HID + kk];
        sh[nn][kk] = v > 0.f ? v : 0.f;   // fused ReLU
    }
    __syncthreads();
    int slot = t >> 5, c = t & 31;
    int gn = nb + slot;
    float al = bl[c], ar = br[c];
#pragma unroll
    for (int k = 0; k < HID; k++) {
        float xv = sh[slot][k];
        al = fmaf(xv, Wl[k * NCLS + c], al);
        ar = fmaf(xv, Wr[k * NCLS + c], ar);
    }
    if (gn < N) {
        xl[(size_t)gn * NCLS + c] = al;
        xr[(size_t)gn * NCLS + c] = ar;
    }
}

// =====================  fused online-softmax aggregation  =====================
// One C-lane group per destination node. Registers hold xr[dst], running
// (m, s) and the C-wide accumulator. Per edge: gather xl[src] (coalesced
// 4B*C), butterfly-reduce the logit, online-softmax update. No atomics.
template <int C>
__global__ __launch_bounds__(256) void fusedAggK(const float* __restrict__ xl,
                                                 const float* __restrict__ xr,
                                                 const float* __restrict__ att,
                                                 const int* __restrict__ rowstart,
                                                 const int* __restrict__ cnt,
                                                 const int* __restrict__ srclist,
                                                 const float* __restrict__ bias,
                                                 float* __restrict__ out, int N) {
    const int NPB = 256 / C;                 // nodes per block
    int sub = threadIdx.x / C;
    int lane = threadIdx.x & (C - 1);
    int n = blockIdx.x * NPB + sub;
    if (n >= N) return;

    float xr_d = xr[(size_t)n * C + lane];
    float att_l = att[lane];
    int row = rowstart[n];
    int deg = cnt[n];

    float m = -INFINITY, s = 0.f, acc = 0.f;
    for (int i = 0; i < deg; i++) {
        int src = srclist[row + i];
        float xls = xl[(size_t)src * C + lane];
        float v = xls + xr_d;
        v = v > 0.f ? v : NEG * v;           // leaky_relu
        float p = v * att_l;
#pragma unroll
        for (int o = C / 2; o > 0; o >>= 1) p += __shfl_xor(p, o, 64);
        float mn = fmaxf(m, p);
        float scale = __expf(m - mn);        // exp(-inf)=0 on first iter
        float w = __expf(p - mn);
        s = s * scale + w;
        acc = acc * scale + w * xls;
        m = mn;
    }
    out[(size_t)n * C + lane] = acc / (s + 1e-16f) + bias[lane];
}

extern "C" void kernel_launch(void* const* d_in, const int* in_sizes, int n_in,
                              void* d_out, int out_size, void* d_ws, size_t ws_size,
                              hipStream_t stream) {
    const float* x     = (const float*)d_in[0];
    const int*   ei    = (const int*)d_in[1];
    const float* W1l   = (const float*)d_in[2];
    const float* b1l   = (const float*)d_in[3];
    const float* W1r   = (const float*)d_in[4];
    const float* b1r   = (const float*)d_in[5];
    const float* att1  = (const float*)d_in[6];
    const float* bias1 = (const float*)d_in[7];
    const float* W2l   = (const float*)d_in[8];
    const float* b2l   = (const float*)d_in[9];
    const float* W2r   = (const float*)d_in[10];
    const float* b2r   = (const float*)d_in[11];
    const float* att2  = (const float*)d_in[12];
    const float* bias2 = (const float*)d_in[13];
    float* out = (float*)d_out;

    int N     = in_sizes[0] / F_IN;   // 100000
    int Eorig = in_sizes[1] / 2;      // 1600000
    int Etot  = Eorig + N;            // with self-loops

    // workspace carve-up (256B aligned)
    char* p = (char*)d_ws;
    auto alloc = [&](size_t bytes) { void* r = (void*)p; p += (bytes + 255) & ~(size_t)255; return r; };
    float* xl1     = (float*)alloc((size_t)N * HID * 4);
    float* xr1     = (float*)alloc((size_t)N * HID * 4);
    float* h       = (float*)alloc((size_t)N * HID * 4);
    float* xl2     = (float*)alloc((size_t)N * NCLS * 4);
    float* xr2     = (float*)alloc((size_t)N * NCLS * 4);
    int*   cnt     = (int*)alloc((size_t)N * 4);
    int*   cursor  = (int*)alloc((size_t)N * 4);
    int*   rowstart= (int*)alloc((size_t)N * 4);
    int*   srclist = (int*)alloc((size_t)Etot * 4);
    int*   bsum    = (int*)alloc(1024 * 4);

    int nb = (N + 1023) / 1024;       // scan blocks (98 for N=100000, must be <=256)
    int gridN = (N + 255) / 256;
    int gridE = (Etot + 255) / 256;

    // ---- CSR build (shared by both layers) ----
    zeroK<<<gridN, 256, 0, stream>>>(cnt, cursor, N);
    histK<<<gridE, 256, 0, stream>>>(ei, Eorig, Etot, cnt);
    scanLocal<<<nb, 256, 0, stream>>>(cnt, rowstart, bsum, N);
    scanBsum<<<1, 256, 0, stream>>>(bsum, nb);
    scanAdd<<<gridN, 256, 0, stream>>>(rowstart, bsum, N);
    scatterK<<<gridE, 256, 0, stream>>>(ei, Eorig, Etot, rowstart, cursor, srclist);

    // ---- layer 1 ----
    transform1<<<(N + 3) / 4, 256, 0, stream>>>(x, W1l, b1l, W1r, b1r, xl1, xr1, N);
    fusedAggK<HID><<<(N + 3) / 4, 256, 0, stream>>>(xl1, xr1, att1, rowstart, cnt,
                                                    srclist, bias1, h, N);

    // ---- layer 2 ----
    transform2<<<(N + 7) / 8, 256, 0, stream>>>(h, W2l, b2l, W2r, b2r, xl2, xr2, N);
    fusedAggK<NCLS><<<(N + 7) / 8, 256, 0, stream>>>(xl2, xr2, att2, rowstart, cnt,
                                                     srclist, bias2, out, N);
}

// Round 4
// 726.010 us; speedup vs baseline: 2.1386x; 1.1507x over previous
//
#include <hip/hip_runtime.h>
#include <math.h>

#define F_IN 128
#define HID 64
#define NCLS 32
#define NEG 0.2f

__device__ __forceinline__ void f4fma(float4& a, float s, const float4& w) {
    a.x = fmaf(s, w.x, a.x);
    a.y = fmaf(s, w.y, a.y);
    a.z = fmaf(s, w.z, a.z);
    a.w = fmaf(s, w.w, a.w);
}

// =====================  CSR build  =====================

__global__ __launch_bounds__(256) void zeroK(int* __restrict__ cnt,
                                             int* __restrict__ cursor, int N) {
    int i = blockIdx.x * 256 + threadIdx.x;
    if (i < N) { cnt[i] = 0; cursor[i] = 0; }
}

__global__ __launch_bounds__(256) void histK(const int* __restrict__ ei,
                                             int Eorig, int Etot,
                                             int* __restrict__ cnt) {
    int edge = blockIdx.x * 256 + threadIdx.x;
    if (edge >= Etot) return;
    int dst = edge < Eorig ? ei[Eorig + edge] : edge - Eorig;
    atomicAdd(&cnt[dst], 1);
}

__global__ __launch_bounds__(256) void scanLocal(const int* __restrict__ cnt,
                                                 int* __restrict__ rowstart,
                                                 int* __restrict__ bsum, int N) {
    __shared__ int sd[256];
    int t = threadIdx.x;
    int base = blockIdx.x * 1024;
    int v[4], tsum = 0;
#pragma unroll
    for (int j = 0; j < 4; j++) {
        int idx = base + t * 4 + j;
        v[j] = idx < N ? cnt[idx] : 0;
        tsum += v[j];
    }
    sd[t] = tsum;
    __syncthreads();
    for (int off = 1; off < 256; off <<= 1) {
        int x = (t >= off) ? sd[t - off] : 0;
        __syncthreads();
        sd[t] += x;
        __syncthreads();
    }
    int run = sd[t] - tsum;
#pragma unroll
    for (int j = 0; j < 4; j++) {
        int idx = base + t * 4 + j;
        if (idx < N) rowstart[idx] = run;
        run += v[j];
    }
    if (t == 255) bsum[blockIdx.x] = sd[255];
}

__global__ __launch_bounds__(256) void scanBsum(int* __restrict__ bsum, int nb) {
    __shared__ int sd[256];
    int t = threadIdx.x;
    int own = t < nb ? bsum[t] : 0;
    sd[t] = own;
    __syncthreads();
    for (int off = 1; off < 256; off <<= 1) {
        int x = (t >= off) ? sd[t - off] : 0;
        __syncthreads();
        sd[t] += x;
        __syncthreads();
    }
    if (t < nb) bsum[t] = sd[t] - own;
}

__global__ __launch_bounds__(256) void scanAdd(int* __restrict__ rowstart,
                                               const int* __restrict__ bsum, int N) {
    int i = blockIdx.x * 256 + threadIdx.x;
    if (i < N) rowstart[i] += bsum[i >> 10];
}

__global__ __launch_bounds__(256) void scatterK(const int* __restrict__ ei,
                                                int Eorig, int Etot,
                                                const int* __restrict__ rowstart,
                                                int* __restrict__ cursor,
                                                int* __restrict__ srclist) {
    int edge = blockIdx.x * 256 + threadIdx.x;
    if (edge >= Etot) return;
    int src, dst;
    if (edge < Eorig) { src = ei[edge]; dst = ei[Eorig + edge]; }
    else              { src = dst = edge - Eorig; }
    int pos = atomicAdd(&cursor[dst], 1);
    srclist[rowstart[dst] + pos] = src;
}

// =====================  dense transforms (register-blocked)  =====================
// transform1: 32 nodes x 64 ch per block. Thread = 4 ch x 2 nodes.
// W loads stay in native [k][ch] layout -> float4 over ch, wave-coalesced.
__global__ __launch_bounds__(256) void transform1(const float* __restrict__ x,
                                                  const float* __restrict__ Wl,
                                                  const float* __restrict__ bl,
                                                  const float* __restrict__ Wr,
                                                  const float* __restrict__ br,
                                                  float* __restrict__ xl,
                                                  float* __restrict__ xr, int N) {
    __shared__ float sx[32][132];   // 32 nodes x 128 k, pad 132 (bank spread)
    int t = threadIdx.x;
    int nb = blockIdx.x * 32;
    // stage x-tile: 1024 float4, 4 per thread
    int maxf = (N - nb) * 32;       // float4 count available
#pragma unroll
    for (int j = 0; j < 4; j++) {
        int f = t + j * 256;        // flat float4 idx: node*32 + kc
        int node = f >> 5, kc = f & 31;
        float4 v = {0.f, 0.f, 0.f, 0.f};
        if (f < maxf) v = ((const float4*)(x + (size_t)nb * F_IN))[f];
        *(float4*)&sx[node][kc * 4] = v;
    }
    __syncthreads();

    int c4 = (t & 15) * 4;          // 4 output channels
    int slot = t >> 4;              // 16 slots x 2 nodes = 32 nodes
    int n0 = slot * 2, n1 = n0 + 1;
    float4 accl0 = *(const float4*)(bl + c4), accl1 = accl0;
    float4 accr0 = *(const float4*)(br + c4), accr1 = accr0;

#pragma unroll 4
    for (int k = 0; k < F_IN; k++) {
        float4 wl = *(const float4*)(Wl + k * HID + c4);
        float4 wr = *(const float4*)(Wr + k * HID + c4);
        float x0 = sx[n0][k], x1 = sx[n1][k];
        f4fma(accl0, x0, wl); f4fma(accl1, x1, wl);
        f4fma(accr0, x0, wr); f4fma(accr1, x1, wr);
    }
    int g0 = nb + n0, g1 = nb + n1;
    if (g0 < N) {
        *(float4*)(xl + (size_t)g0 * HID + c4) = accl0;
        *(float4*)(xr + (size_t)g0 * HID + c4) = accr0;
    }
    if (g1 < N) {
        *(float4*)(xl + (size_t)g1 * HID + c4) = accl1;
        *(float4*)(xr + (size_t)g1 * HID + c4) = accr1;
    }
}

// transform2: 64 nodes x 32 ch per block, ReLU fused on LDS stage.
__global__ __launch_bounds__(256) void transform2(const float* __restrict__ h,
                                                  const float* __restrict__ Wl,
                                                  const float* __restrict__ bl,
                                                  const float* __restrict__ Wr,
                                                  const float* __restrict__ br,
                                                  float* __restrict__ xl,
                                                  float* __restrict__ xr, int N) {
    __shared__ float sh[64][68];    // 64 nodes x 64 k, pad 68
    int t = threadIdx.x;
    int nb = blockIdx.x * 64;
    int maxf = (N - nb) * 16;       // float4 per row = 16
#pragma unroll
    for (int j = 0; j < 4; j++) {
        int f = t + j * 256;        // node*16 + kc
        int node = f >> 4, kc = f & 15;
        float4 v = {0.f, 0.f, 0.f, 0.f};
        if (f < maxf) v = ((const float4*)(h + (size_t)nb * HID))[f];
        v.x = v.x > 0.f ? v.x : 0.f;
        v.y = v.y > 0.f ? v.y : 0.f;
        v.z = v.z > 0.f ? v.z : 0.f;
        v.w = v.w > 0.f ? v.w : 0.f;
        *(float4*)&sh[node][kc * 4] = v;
    }
    __syncthreads();

    int c4 = (t & 7) * 4;           // 4 of 32 channels
    int slot = t >> 3;              // 32 slots x 2 nodes = 64 nodes
    int n0 = slot * 2, n1 = n0 + 1;
    float4 accl0 = *(const float4*)(bl + c4), accl1 = accl0;
    float4 accr0 = *(const float4*)(br + c4), accr1 = accr0;

#pragma unroll 4
    for (int k = 0; k < HID; k++) {
        float4 wl = *(const float4*)(Wl + k * NCLS + c4);
        float4 wr = *(const float4*)(Wr + k * NCLS + c4);
        float x0 = sh[n0][k], x1 = sh[n1][k];
        f4fma(accl0, x0, wl); f4fma(accl1, x1, wl);
        f4fma(accr0, x0, wr); f4fma(accr1, x1, wr);
    }
    int g0 = nb + n0, g1 = nb + n1;
    if (g0 < N) {
        *(float4*)(xl + (size_t)g0 * NCLS + c4) = accl0;
        *(float4*)(xr + (size_t)g0 * NCLS + c4) = accr0;
    }
    if (g1 < N) {
        *(float4*)(xl + (size_t)g1 * NCLS + c4) = accl1;
        *(float4*)(xr + (size_t)g1 * NCLS + c4) = accr1;
    }
}

// =====================  fused online-softmax aggregation  =====================
template <int C>
__global__ __launch_bounds__(256) void fusedAggK(const float* __restrict__ xl,
                                                 const float* __restrict__ xr,
                                                 const float* __restrict__ att,
                                                 const int* __restrict__ rowstart,
                                                 const int* __restrict__ cnt,
                                                 const int* __restrict__ srclist,
                                                 const float* __restrict__ bias,
                                                 float* __restrict__ out, int N) {
    const int NPB = 256 / C;
    int sub = threadIdx.x / C;
    int lane = threadIdx.x & (C - 1);
    int n = blockIdx.x * NPB + sub;
    if (n >= N) return;

    float xr_d = xr[(size_t)n * C + lane];
    float att_l = att[lane];
    int row = rowstart[n];
    int deg = cnt[n];

    float m = -INFINITY, s = 0.f, acc = 0.f;
    for (int i = 0; i < deg; i++) {
        int src = srclist[row + i];
        float xls = xl[(size_t)src * C + lane];
        float v = xls + xr_d;
        v = v > 0.f ? v : NEG * v;
        float p = v * att_l;
#pragma unroll
        for (int o = C / 2; o > 0; o >>= 1) p += __shfl_xor(p, o, 64);
        float mn = fmaxf(m, p);
        float scale = __expf(m - mn);
        float w = __expf(p - mn);
        s = s * scale + w;
        acc = acc * scale + w * xls;
        m = mn;
    }
    out[(size_t)n * C + lane] = acc / (s + 1e-16f) + bias[lane];
}

extern "C" void kernel_launch(void* const* d_in, const int* in_sizes, int n_in,
                              void* d_out, int out_size, void* d_ws, size_t ws_size,
                              hipStream_t stream) {
    const float* x     = (const float*)d_in[0];
    const int*   ei    = (const int*)d_in[1];
    const float* W1l   = (const float*)d_in[2];
    const float* b1l   = (const float*)d_in[3];
    const float* W1r   = (const float*)d_in[4];
    const float* b1r   = (const float*)d_in[5];
    const float* att1  = (const float*)d_in[6];
    const float* bias1 = (const float*)d_in[7];
    const float* W2l   = (const float*)d_in[8];
    const float* b2l   = (const float*)d_in[9];
    const float* W2r   = (const float*)d_in[10];
    const float* b2r   = (const float*)d_in[11];
    const float* att2  = (const float*)d_in[12];
    const float* bias2 = (const float*)d_in[13];
    float* out = (float*)d_out;

    int N     = in_sizes[0] / F_IN;   // 100000
    int Eorig = in_sizes[1] / 2;      // 1600000
    int Etot  = Eorig + N;

    char* p = (char*)d_ws;
    auto alloc = [&](size_t bytes) { void* r = (void*)p; p += (bytes + 255) & ~(size_t)255; return r; };
    float* xl1     = (float*)alloc((size_t)N * HID * 4);
    float* xr1     = (float*)alloc((size_t)N * HID * 4);
    float* h       = (float*)alloc((size_t)N * HID * 4);
    float* xl2     = (float*)alloc((size_t)N * NCLS * 4);
    float* xr2     = (float*)alloc((size_t)N * NCLS * 4);
    int*   cnt     = (int*)alloc((size_t)N * 4);
    int*   cursor  = (int*)alloc((size_t)N * 4);
    int*   rowstart= (int*)alloc((size_t)N * 4);
    int*   srclist = (int*)alloc((size_t)Etot * 4);
    int*   bsum    = (int*)alloc(1024 * 4);

    int nb = (N + 1023) / 1024;
    int gridN = (N + 255) / 256;
    int gridE = (Etot + 255) / 256;

    // ---- CSR build (shared by both layers) ----
    zeroK<<<gridN, 256, 0, stream>>>(cnt, cursor, N);
    histK<<<gridE, 256, 0, stream>>>(ei, Eorig, Etot, cnt);
    scanLocal<<<nb, 256, 0, stream>>>(cnt, rowstart, bsum, N);
    scanBsum<<<1, 256, 0, stream>>>(bsum, nb);
    scanAdd<<<gridN, 256, 0, stream>>>(rowstart, bsum, N);
    scatterK<<<gridE, 256, 0, stream>>>(ei, Eorig, Etot, rowstart, cursor, srclist);

    // ---- layer 1 ----
    transform1<<<(N + 31) / 32, 256, 0, stream>>>(x, W1l, b1l, W1r, b1r, xl1, xr1, N);
    fusedAggK<HID><<<(N + 3) / 4, 256, 0, stream>>>(xl1, xr1, att1, rowstart, cnt,
                                                    srclist, bias1, h, N);

    // ---- layer 2 ----
    transform2<<<(N + 63) / 64, 256, 0, stream>>>(h, W2l, b2l, W2r, b2r, xl2, xr2, N);
    fusedAggK<NCLS><<<(N + 7) / 8, 256, 0, stream>>>(xl2, xr2, att2, rowstart, cnt,
                                                     srclist, bias2, out, N);
}

// Round 5
// 576.116 us; speedup vs baseline: 2.6951x; 1.2602x over previous
//
#include <hip/hip_runtime.h>
#include <math.h>

#define F_IN 128
#define HID 64
#define NCLS 32
#define NEG 0.2f

__device__ __forceinline__ void f4fma(float4& a, float s, const float4& w) {
    a.x = fmaf(s, w.x, a.x);
    a.y = fmaf(s, w.y, a.y);
    a.z = fmaf(s, w.z, a.z);
    a.w = fmaf(s, w.w, a.w);
}

// =====================  CSR build  =====================

__global__ __launch_bounds__(256) void zeroK(int* __restrict__ cnt,
                                             int* __restrict__ cursor, int N) {
    int i = blockIdx.x * 256 + threadIdx.x;
    if (i < N) { cnt[i] = 0; cursor[i] = 0; }
}

__global__ __launch_bounds__(256) void histK(const int* __restrict__ ei,
                                             int Eorig, int Etot,
                                             int* __restrict__ cnt) {
    int edge = blockIdx.x * 256 + threadIdx.x;
    if (edge >= Etot) return;
    int dst = edge < Eorig ? ei[Eorig + edge] : edge - Eorig;
    atomicAdd(&cnt[dst], 1);
}

__global__ __launch_bounds__(256) void scanLocal(const int* __restrict__ cnt,
                                                 int* __restrict__ rowstart,
                                                 int* __restrict__ bsum, int N) {
    __shared__ int sd[256];
    int t = threadIdx.x;
    int base = blockIdx.x * 1024;
    int v[4], tsum = 0;
#pragma unroll
    for (int j = 0; j < 4; j++) {
        int idx = base + t * 4 + j;
        v[j] = idx < N ? cnt[idx] : 0;
        tsum += v[j];
    }
    sd[t] = tsum;
    __syncthreads();
    for (int off = 1; off < 256; off <<= 1) {
        int x = (t >= off) ? sd[t - off] : 0;
        __syncthreads();
        sd[t] += x;
        __syncthreads();
    }
    int run = sd[t] - tsum;
#pragma unroll
    for (int j = 0; j < 4; j++) {
        int idx = base + t * 4 + j;
        if (idx < N) rowstart[idx] = run;
        run += v[j];
    }
    if (t == 255) bsum[blockIdx.x] = sd[255];
}

__global__ __launch_bounds__(256) void scanBsum(int* __restrict__ bsum, int nb) {
    __shared__ int sd[256];
    int t = threadIdx.x;
    int own = t < nb ? bsum[t] : 0;
    sd[t] = own;
    __syncthreads();
    for (int off = 1; off < 256; off <<= 1) {
        int x = (t >= off) ? sd[t - off] : 0;
        __syncthreads();
        sd[t] += x;
        __syncthreads();
    }
    if (t < nb) bsum[t] = sd[t] - own;
}

__global__ __launch_bounds__(256) void scanAdd(int* __restrict__ rowstart,
                                               const int* __restrict__ bsum, int N) {
    int i = blockIdx.x * 256 + threadIdx.x;
    if (i < N) rowstart[i] += bsum[i >> 10];
}

__global__ __launch_bounds__(256) void scatterK(const int* __restrict__ ei,
                                                int Eorig, int Etot,
                                                const int* __restrict__ rowstart,
                                                int* __restrict__ cursor,
                                                int* __restrict__ srclist) {
    int edge = blockIdx.x * 256 + threadIdx.x;
    if (edge >= Etot) return;
    int src, dst;
    if (edge < Eorig) { src = ei[edge]; dst = ei[Eorig + edge]; }
    else              { src = dst = edge - Eorig; }
    int pos = atomicAdd(&cursor[dst], 1);
    srclist[rowstart[dst] + pos] = src;
}

// =====================  dense transforms (register-blocked)  =====================

__global__ __launch_bounds__(256) void transform1(const float* __restrict__ x,
                                                  const float* __restrict__ Wl,
                                                  const float* __restrict__ bl,
                                                  const float* __restrict__ Wr,
                                                  const float* __restrict__ br,
                                                  float* __restrict__ xl,
                                                  float* __restrict__ xr, int N) {
    __shared__ float sx[32][132];
    int t = threadIdx.x;
    int nb = blockIdx.x * 32;
    int maxf = (N - nb) * 32;
#pragma unroll
    for (int j = 0; j < 4; j++) {
        int f = t + j * 256;
        int node = f >> 5, kc = f & 31;
        float4 v = {0.f, 0.f, 0.f, 0.f};
        if (f < maxf) v = ((const float4*)(x + (size_t)nb * F_IN))[f];
        *(float4*)&sx[node][kc * 4] = v;
    }
    __syncthreads();

    int c4 = (t & 15) * 4;
    int slot = t >> 4;
    int n0 = slot * 2, n1 = n0 + 1;
    float4 accl0 = *(const float4*)(bl + c4), accl1 = accl0;
    float4 accr0 = *(const float4*)(br + c4), accr1 = accr0;

#pragma unroll 4
    for (int k = 0; k < F_IN; k++) {
        float4 wl = *(const float4*)(Wl + k * HID + c4);
        float4 wr = *(const float4*)(Wr + k * HID + c4);
        float x0 = sx[n0][k], x1 = sx[n1][k];
        f4fma(accl0, x0, wl); f4fma(accl1, x1, wl);
        f4fma(accr0, x0, wr); f4fma(accr1, x1, wr);
    }
    int g0 = nb + n0, g1 = nb + n1;
    if (g0 < N) {
        *(float4*)(xl + (size_t)g0 * HID + c4) = accl0;
        *(float4*)(xr + (size_t)g0 * HID + c4) = accr0;
    }
    if (g1 < N) {
        *(float4*)(xl + (size_t)g1 * HID + c4) = accl1;
        *(float4*)(xr + (size_t)g1 * HID + c4) = accr1;
    }
}

__global__ __launch_bounds__(256) void transform2(const float* __restrict__ h,
                                                  const float* __restrict__ Wl,
                                                  const float* __restrict__ bl,
                                                  const float* __restrict__ Wr,
                                                  const float* __restrict__ br,
                                                  float* __restrict__ xl,
                                                  float* __restrict__ xr, int N) {
    __shared__ float sh[64][68];
    int t = threadIdx.x;
    int nb = blockIdx.x * 64;
    int maxf = (N - nb) * 16;
#pragma unroll
    for (int j = 0; j < 4; j++) {
        int f = t + j * 256;
        int node = f >> 4, kc = f & 15;
        float4 v = {0.f, 0.f, 0.f, 0.f};
        if (f < maxf) v = ((const float4*)(h + (size_t)nb * HID))[f];
        v.x = v.x > 0.f ? v.x : 0.f;
        v.y = v.y > 0.f ? v.y : 0.f;
        v.z = v.z > 0.f ? v.z : 0.f;
        v.w = v.w > 0.f ? v.w : 0.f;
        *(float4*)&sh[node][kc * 4] = v;
    }
    __syncthreads();

    int c4 = (t & 7) * 4;
    int slot = t >> 3;
    int n0 = slot * 2, n1 = n0 + 1;
    float4 accl0 = *(const float4*)(bl + c4), accl1 = accl0;
    float4 accr0 = *(const float4*)(br + c4), accr1 = accr0;

#pragma unroll 4
    for (int k = 0; k < HID; k++) {
        float4 wl = *(const float4*)(Wl + k * NCLS + c4);
        float4 wr = *(const float4*)(Wr + k * NCLS + c4);
        float x0 = sh[n0][k], x1 = sh[n1][k];
        f4fma(accl0, x0, wl); f4fma(accl1, x1, wl);
        f4fma(accr0, x0, wr); f4fma(accr1, x1, wr);
    }
    int g0 = nb + n0, g1 = nb + n1;
    if (g0 < N) {
        *(float4*)(xl + (size_t)g0 * NCLS + c4) = accl0;
        *(float4*)(xr + (size_t)g0 * NCLS + c4) = accr0;
    }
    if (g1 < N) {
        *(float4*)(xl + (size_t)g1 * NCLS + c4) = accl1;
        *(float4*)(xr + (size_t)g1 * NCLS + c4) = accr1;
    }
}

// =====================  fused softmax aggregation, v3  =====================
// One 64-lane wave per node. Edges in chunks of <=64.
// Phase 1: SLOTS edges in flight per instruction (C/4 lanes x float4 each),
//          shallow intra-slot shuffle reduce; logits collected lane-per-edge.
// Softmax: lane-parallel over the whole chunk (2 butterflies per 64 edges).
// Phase 2: SLOTS edges per instruction, per-slot float4 partial accumulators,
//          combined at the end. All cross-lane via registers (wave-synchronous).
template <int C>
__global__ __launch_bounds__(256) void fusedAggK(const float* __restrict__ xl,
                                                 const float* __restrict__ xr,
                                                 const float* __restrict__ att,
                                                 const int* __restrict__ rowstart,
                                                 const int* __restrict__ cnt,
                                                 const int* __restrict__ srclist,
                                                 const float* __restrict__ bias,
                                                 float* __restrict__ out, int N) {
    const int LPQ = C / 4;          // lanes per edge slot
    const int SLOTS = 64 / LPQ;     // edges in flight per wave (4 or 8)
    int wid = threadIdx.x >> 6;
    int lane = threadIdx.x & 63;
    int n = blockIdx.x * 4 + wid;   // 4 waves/block = 4 nodes/block
    if (n >= N) return;

    int slot = lane / LPQ;
    int pos = lane % LPQ;
    int c4 = pos * 4;

    float4 xr4 = *(const float4*)(xr + (size_t)n * C + c4);
    float4 at4 = *(const float4*)(att + c4);
    float4 bi4 = *(const float4*)(bias + c4);

    int row = rowstart[n];
    int deg = cnt[n];

    float m = -INFINITY, s = 0.f;
    float4 acc = {0.f, 0.f, 0.f, 0.f};

    for (int cb = 0; cb < deg; cb += 64) {
        int len = deg - cb; if (len > 64) len = 64;
        // lane i holds src of chunk-edge i (clamped for OOB lanes)
        int li = lane < len ? lane : len - 1;
        int srcreg = srclist[row + cb + li];

        int nbatch = (len + SLOTS - 1) / SLOTS;
        // ---- phase 1: logits, SLOTS edges per pass ----
        float myp = 0.f;
#pragma unroll 2
        for (int b = 0; b < nbatch; b++) {
            int eidx = b * SLOTS + slot;          // < 64 always
            int src = __shfl(srcreg, eidx, 64);
            float4 v = *(const float4*)(xl + (size_t)src * C + c4);
            v.x += xr4.x; v.y += xr4.y; v.z += xr4.z; v.w += xr4.w;
            v.x = fmaxf(v.x, NEG * v.x);
            v.y = fmaxf(v.y, NEG * v.y);
            v.z = fmaxf(v.z, NEG * v.z);
            v.w = fmaxf(v.w, NEG * v.w);
            float p = v.x * at4.x;
            p = fmaf(v.y, at4.y, p);
            p = fmaf(v.z, at4.z, p);
            p = fmaf(v.w, at4.w, p);
#pragma unroll
            for (int o = 1; o < LPQ; o <<= 1) p += __shfl_xor(p, o, 64);
            // collect: lane i takes edge i's logit during batch i/SLOTS
            float got = __shfl(p, (lane & (SLOTS - 1)) * LPQ, 64);
            myp = (b == lane / SLOTS) ? got : myp;
        }
        // ---- chunk softmax (lane-parallel) ----
        float pv = (lane < len) ? myp : -INFINITY;
        float cmax = pv;
#pragma unroll
        for (int o = 1; o < 64; o <<= 1) cmax = fmaxf(cmax, __shfl_xor(cmax, o, 64));
        float mn = fmaxf(m, cmax);
        float ex = (lane < len) ? __expf(myp - mn) : 0.f;
        float csum = ex;
#pragma unroll
        for (int o = 1; o < 64; o <<= 1) csum += __shfl_xor(csum, o, 64);
        float alpha = __expf(m - mn);             // first chunk: exp(-inf)=0
        s = s * alpha + csum;
        acc.x *= alpha; acc.y *= alpha; acc.z *= alpha; acc.w *= alpha;
        m = mn;
        // ---- phase 2: weighted accumulate, SLOTS edges per pass ----
#pragma unroll 2
        for (int b = 0; b < nbatch; b++) {
            int eidx = b * SLOTS + slot;
            float w = __shfl(ex, eidx, 64);       // 0 for invalid edges
            int src = __shfl(srcreg, eidx, 64);
            float4 v = *(const float4*)(xl + (size_t)src * C + c4);
            acc.x = fmaf(w, v.x, acc.x);
            acc.y = fmaf(w, v.y, acc.y);
            acc.z = fmaf(w, v.z, acc.z);
            acc.w = fmaf(w, v.w, acc.w);
        }
    }
    // combine per-slot partials (butterfly over slot bits)
#pragma unroll
    for (int o = LPQ; o < 64; o <<= 1) {
        acc.x += __shfl_xor(acc.x, o, 64);
        acc.y += __shfl_xor(acc.y, o, 64);
        acc.z += __shfl_xor(acc.z, o, 64);
        acc.w += __shfl_xor(acc.w, o, 64);
    }
    if (lane < LPQ) {
        float inv = 1.f / (s + 1e-16f);
        float4 o4;
        o4.x = acc.x * inv + bi4.x;
        o4.y = acc.y * inv + bi4.y;
        o4.z = acc.z * inv + bi4.z;
        o4.w = acc.w * inv + bi4.w;
        *(float4*)(out + (size_t)n * C + c4) = o4;
    }
}

extern "C" void kernel_launch(void* const* d_in, const int* in_sizes, int n_in,
                              void* d_out, int out_size, void* d_ws, size_t ws_size,
                              hipStream_t stream) {
    const float* x     = (const float*)d_in[0];
    const int*   ei    = (const int*)d_in[1];
    const float* W1l   = (const float*)d_in[2];
    const float* b1l   = (const float*)d_in[3];
    const float* W1r   = (const float*)d_in[4];
    const float* b1r   = (const float*)d_in[5];
    const float* att1  = (const float*)d_in[6];
    const float* bias1 = (const float*)d_in[7];
    const float* W2l   = (const float*)d_in[8];
    const float* b2l   = (const float*)d_in[9];
    const float* W2r   = (const float*)d_in[10];
    const float* b2r   = (const float*)d_in[11];
    const float* att2  = (const float*)d_in[12];
    const float* bias2 = (const float*)d_in[13];
    float* out = (float*)d_out;

    int N     = in_sizes[0] / F_IN;   // 100000
    int Eorig = in_sizes[1] / 2;      // 1600000
    int Etot  = Eorig + N;

    char* p = (char*)d_ws;
    auto alloc = [&](size_t bytes) { void* r = (void*)p; p += (bytes + 255) & ~(size_t)255; return r; };
    float* xl1     = (float*)alloc((size_t)N * HID * 4);
    float* xr1     = (float*)alloc((size_t)N * HID * 4);
    float* h       = (float*)alloc((size_t)N * HID * 4);
    float* xl2     = (float*)alloc((size_t)N * NCLS * 4);
    float* xr2     = (float*)alloc((size_t)N * NCLS * 4);
    int*   cnt     = (int*)alloc((size_t)N * 4);
    int*   cursor  = (int*)alloc((size_t)N * 4);
    int*   rowstart= (int*)alloc((size_t)N * 4);
    int*   srclist = (int*)alloc((size_t)Etot * 4);
    int*   bsum    = (int*)alloc(1024 * 4);

    int nb = (N + 1023) / 1024;
    int gridN = (N + 255) / 256;
    int gridE = (Etot + 255) / 256;

    // ---- CSR build (shared by both layers) ----
    zeroK<<<gridN, 256, 0, stream>>>(cnt, cursor, N);
    histK<<<gridE, 256, 0, stream>>>(ei, Eorig, Etot, cnt);
    scanLocal<<<nb, 256, 0, stream>>>(cnt, rowstart, bsum, N);
    scanBsum<<<1, 256, 0, stream>>>(bsum, nb);
    scanAdd<<<gridN, 256, 0, stream>>>(rowstart, bsum, N);
    scatterK<<<gridE, 256, 0, stream>>>(ei, Eorig, Etot, rowstart, cursor, srclist);

    // ---- layer 1 ----
    transform1<<<(N + 31) / 32, 256, 0, stream>>>(x, W1l, b1l, W1r, b1r, xl1, xr1, N);
    fusedAggK<HID><<<(N + 3) / 4, 256, 0, stream>>>(xl1, xr1, att1, rowstart, cnt,
                                                    srclist, bias1, h, N);

    // ---- layer 2 ----
    transform2<<<(N + 63) / 64, 256, 0, stream>>>(h, W2l, b2l, W2r, b2r, xl2, xr2, N);
    fusedAggK<NCLS><<<(N + 3) / 4, 256, 0, stream>>>(xl2, xr2, att2, rowstart, cnt,
                                                     srclist, bias2, out, N);
}

// Round 6
// 521.490 us; speedup vs baseline: 2.9774x; 1.1047x over previous
//
#include <hip/hip_runtime.h>
#include <math.h>

#define F_IN 128
#define HID 64
#define NCLS 32
#define NEG 0.2f

__device__ __forceinline__ void f4fma(float4& a, float s, const float4& w) {
    a.x = fmaf(s, w.x, a.x);
    a.y = fmaf(s, w.y, a.y);
    a.z = fmaf(s, w.z, a.z);
    a.w = fmaf(s, w.w, a.w);
}

// =====================  CSR build  =====================

__global__ __launch_bounds__(256) void zeroK(int* __restrict__ cnt,
                                             int* __restrict__ cursor, int N) {
    int i = blockIdx.x * 256 + threadIdx.x;
    if (i < N) { cnt[i] = 0; cursor[i] = 0; }
}

__global__ __launch_bounds__(256) void histK(const int* __restrict__ ei,
                                             int Eorig, int Etot,
                                             int* __restrict__ cnt) {
    int edge = blockIdx.x * 256 + threadIdx.x;
    if (edge >= Etot) return;
    int dst = edge < Eorig ? ei[Eorig + edge] : edge - Eorig;
    atomicAdd(&cnt[dst], 1);
}

__global__ __launch_bounds__(256) void scanLocal(const int* __restrict__ cnt,
                                                 int* __restrict__ rowstart,
                                                 int* __restrict__ bsum, int N) {
    __shared__ int sd[256];
    int t = threadIdx.x;
    int base = blockIdx.x * 1024;
    int v[4], tsum = 0;
#pragma unroll
    for (int j = 0; j < 4; j++) {
        int idx = base + t * 4 + j;
        v[j] = idx < N ? cnt[idx] : 0;
        tsum += v[j];
    }
    sd[t] = tsum;
    __syncthreads();
    for (int off = 1; off < 256; off <<= 1) {
        int x = (t >= off) ? sd[t - off] : 0;
        __syncthreads();
        sd[t] += x;
        __syncthreads();
    }
    int run = sd[t] - tsum;
#pragma unroll
    for (int j = 0; j < 4; j++) {
        int idx = base + t * 4 + j;
        if (idx < N) rowstart[idx] = run;
        run += v[j];
    }
    if (t == 255) bsum[blockIdx.x] = sd[255];
}

__global__ __launch_bounds__(256) void scanBsum(int* __restrict__ bsum, int nb) {
    __shared__ int sd[256];
    int t = threadIdx.x;
    int own = t < nb ? bsum[t] : 0;
    sd[t] = own;
    __syncthreads();
    for (int off = 1; off < 256; off <<= 1) {
        int x = (t >= off) ? sd[t - off] : 0;
        __syncthreads();
        sd[t] += x;
        __syncthreads();
    }
    if (t < nb) bsum[t] = sd[t] - own;
}

__global__ __launch_bounds__(256) void scanAdd(int* __restrict__ rowstart,
                                               const int* __restrict__ bsum, int N) {
    int i = blockIdx.x * 256 + threadIdx.x;
    if (i < N) rowstart[i] += bsum[i >> 10];
}

__global__ __launch_bounds__(256) void scatterK(const int* __restrict__ ei,
                                                int Eorig, int Etot,
                                                const int* __restrict__ rowstart,
                                                int* __restrict__ cursor,
                                                int* __restrict__ srclist) {
    int edge = blockIdx.x * 256 + threadIdx.x;
    if (edge >= Etot) return;
    int src, dst;
    if (edge < Eorig) { src = ei[edge]; dst = ei[Eorig + edge]; }
    else              { src = dst = edge - Eorig; }
    int pos = atomicAdd(&cursor[dst], 1);
    srclist[rowstart[dst] + pos] = src;
}

// =====================  dense transforms (LDS-staged W, v2)  =====================
// transform1: 64 nodes x 64 ch per block; blockIdx.y picks (Wl,bl,xl)/(Wr,br,xr).
// W (32KB) + x-tile (33.8KB) in LDS -> all inner-loop reads ~30cyc LDS, not L2.
// Thread = 4 ch x 4 nodes (nodes strided by 16 for conflict-free LDS banks).
__global__ __launch_bounds__(256) void transform1(const float* __restrict__ x,
                                                  const float* __restrict__ Wl,
                                                  const float* __restrict__ bl,
                                                  const float* __restrict__ Wr,
                                                  const float* __restrict__ br,
                                                  float* __restrict__ xl,
                                                  float* __restrict__ xr, int N) {
    __shared__ float sW[F_IN * HID];   // 32KB, [k][c] flat
    __shared__ float sx[64][132];      // [node][k], pad 132 (16B-aligned rows)
    const float* W = blockIdx.y ? Wr : Wl;
    const float* b = blockIdx.y ? br : bl;
    float* o       = blockIdx.y ? xr : xl;
    int t = threadIdx.x;
    int nb = blockIdx.x * 64;

    // stage W: 2048 float4, consecutive = conflict-free
#pragma unroll
    for (int j = 0; j < 8; j++) {
        int f = t + j * 256;
        ((float4*)sW)[f] = ((const float4*)W)[f];
    }
    // stage x-tile: 64 nodes x 32 float4 (k-contiguous)
    int maxf = (N - nb) * 32;
#pragma unroll
    for (int j = 0; j < 8; j++) {
        int f = t + j * 256;
        int node = f >> 5, kc = f & 31;
        float4 v = {0.f, 0.f, 0.f, 0.f};
        if (f < maxf) v = ((const float4*)(x + (size_t)nb * F_IN))[f];
        *(float4*)&sx[node][kc * 4] = v;
    }
    __syncthreads();

    int c4 = (t & 15) * 4;   // 16 channel groups
    int slot = t >> 4;       // 16 slots; nodes = slot + j*16
    float4 b4 = *(const float4*)(b + c4);
    float4 acc[4] = {b4, b4, b4, b4};

#pragma unroll 4
    for (int k4 = 0; k4 < F_IN / 4; k4++) {
        int k = k4 * 4;
        float4 w0 = *(const float4*)&sW[(k + 0) * HID + c4];
        float4 w1 = *(const float4*)&sW[(k + 1) * HID + c4];
        float4 w2 = *(const float4*)&sW[(k + 2) * HID + c4];
        float4 w3 = *(const float4*)&sW[(k + 3) * HID + c4];
#pragma unroll
        for (int j = 0; j < 4; j++) {
            float4 xv = *(const float4*)&sx[slot + j * 16][k];
            f4fma(acc[j], xv.x, w0);
            f4fma(acc[j], xv.y, w1);
            f4fma(acc[j], xv.z, w2);
            f4fma(acc[j], xv.w, w3);
        }
    }
#pragma unroll
    for (int j = 0; j < 4; j++) {
        int g = nb + slot + j * 16;
        if (g < N) *(float4*)(o + (size_t)g * HID + c4) = acc[j];
    }
}

// transform2: 128 nodes x 32 ch, both matrices per block (W 16KB in LDS),
// ReLU fused at stage. Thread = 4 ch x 4 nodes (strided by 32).
__global__ __launch_bounds__(256) void transform2(const float* __restrict__ h,
                                                  const float* __restrict__ Wl,
                                                  const float* __restrict__ bl,
                                                  const float* __restrict__ Wr,
                                                  const float* __restrict__ br,
                                                  float* __restrict__ xl,
                                                  float* __restrict__ xr, int N) {
    __shared__ float sWl[HID * NCLS];  // 8KB
    __shared__ float sWr[HID * NCLS];  // 8KB
    __shared__ float sx[128][68];      // 34.8KB, [node][k]
    int t = threadIdx.x;
    int nb = blockIdx.x * 128;

#pragma unroll
    for (int j = 0; j < 2; j++) {
        int f = t + j * 256;
        ((float4*)sWl)[f] = ((const float4*)Wl)[f];
        ((float4*)sWr)[f] = ((const float4*)Wr)[f];
    }
    int maxf = (N - nb) * 16;
#pragma unroll
    for (int j = 0; j < 8; j++) {
        int f = t + j * 256;
        int node = f >> 4, kc = f & 15;
        float4 v = {0.f, 0.f, 0.f, 0.f};
        if (f < maxf) v = ((const float4*)(h + (size_t)nb * HID))[f];
        v.x = fmaxf(v.x, 0.f);
        v.y = fmaxf(v.y, 0.f);
        v.z = fmaxf(v.z, 0.f);
        v.w = fmaxf(v.w, 0.f);
        *(float4*)&sx[node][kc * 4] = v;
    }
    __syncthreads();

    int c4 = (t & 7) * 4;    // 8 channel groups
    int slot = t >> 3;       // 32 slots; nodes = slot + j*32
    float4 bl4 = *(const float4*)(bl + c4);
    float4 br4 = *(const float4*)(br + c4);
    float4 accl[4] = {bl4, bl4, bl4, bl4};
    float4 accr[4] = {br4, br4, br4, br4};

#pragma unroll 4
    for (int k4 = 0; k4 < HID / 4; k4++) {
        int k = k4 * 4;
        float4 wl0 = *(const float4*)&sWl[(k + 0) * NCLS + c4];
        float4 wl1 = *(const float4*)&sWl[(k + 1) * NCLS + c4];
        float4 wl2 = *(const float4*)&sWl[(k + 2) * NCLS + c4];
        float4 wl3 = *(const float4*)&sWl[(k + 3) * NCLS + c4];
        float4 wr0 = *(const float4*)&sWr[(k + 0) * NCLS + c4];
        float4 wr1 = *(const float4*)&sWr[(k + 1) * NCLS + c4];
        float4 wr2 = *(const float4*)&sWr[(k + 2) * NCLS + c4];
        float4 wr3 = *(const float4*)&sWr[(k + 3) * NCLS + c4];
#pragma unroll
        for (int j = 0; j < 4; j++) {
            float4 xv = *(const float4*)&sx[slot + j * 32][k];
            f4fma(accl[j], xv.x, wl0); f4fma(accr[j], xv.x, wr0);
            f4fma(accl[j], xv.y, wl1); f4fma(accr[j], xv.y, wr1);
            f4fma(accl[j], xv.z, wl2); f4fma(accr[j], xv.z, wr2);
            f4fma(accl[j], xv.w, wl3); f4fma(accr[j], xv.w, wr3);
        }
    }
#pragma unroll
    for (int j = 0; j < 4; j++) {
        int g = nb + slot + j * 32;
        if (g < N) {
            *(float4*)(xl + (size_t)g * NCLS + c4) = accl[j];
            *(float4*)(xr + (size_t)g * NCLS + c4) = accr[j];
        }
    }
}

// =====================  fused softmax aggregation (v3, unchanged)  =====================
template <int C>
__global__ __launch_bounds__(256) void fusedAggK(const float* __restrict__ xl,
                                                 const float* __restrict__ xr,
                                                 const float* __restrict__ att,
                                                 const int* __restrict__ rowstart,
                                                 const int* __restrict__ cnt,
                                                 const int* __restrict__ srclist,
                                                 const float* __restrict__ bias,
                                                 float* __restrict__ out, int N) {
    const int LPQ = C / 4;
    const int SLOTS = 64 / LPQ;
    int wid = threadIdx.x >> 6;
    int lane = threadIdx.x & 63;
    int n = blockIdx.x * 4 + wid;
    if (n >= N) return;

    int slot = lane / LPQ;
    int pos = lane % LPQ;
    int c4 = pos * 4;

    float4 xr4 = *(const float4*)(xr + (size_t)n * C + c4);
    float4 at4 = *(const float4*)(att + c4);
    float4 bi4 = *(const float4*)(bias + c4);

    int row = rowstart[n];
    int deg = cnt[n];

    float m = -INFINITY, s = 0.f;
    float4 acc = {0.f, 0.f, 0.f, 0.f};

    for (int cb = 0; cb < deg; cb += 64) {
        int len = deg - cb; if (len > 64) len = 64;
        int li = lane < len ? lane : len - 1;
        int srcreg = srclist[row + cb + li];

        int nbatch = (len + SLOTS - 1) / SLOTS;
        float myp = 0.f;
#pragma unroll 2
        for (int b = 0; b < nbatch; b++) {
            int eidx = b * SLOTS + slot;
            int src = __shfl(srcreg, eidx, 64);
            float4 v = *(const float4*)(xl + (size_t)src * C + c4);
            v.x += xr4.x; v.y += xr4.y; v.z += xr4.z; v.w += xr4.w;
            v.x = fmaxf(v.x, NEG * v.x);
            v.y = fmaxf(v.y, NEG * v.y);
            v.z = fmaxf(v.z, NEG * v.z);
            v.w = fmaxf(v.w, NEG * v.w);
            float p = v.x * at4.x;
            p = fmaf(v.y, at4.y, p);
            p = fmaf(v.z, at4.z, p);
            p = fmaf(v.w, at4.w, p);
#pragma unroll
            for (int o = 1; o < LPQ; o <<= 1) p += __shfl_xor(p, o, 64);
            float got = __shfl(p, (lane & (SLOTS - 1)) * LPQ, 64);
            myp = (b == lane / SLOTS) ? got : myp;
        }
        float pv = (lane < len) ? myp : -INFINITY;
        float cmax = pv;
#pragma unroll
        for (int o = 1; o < 64; o <<= 1) cmax = fmaxf(cmax, __shfl_xor(cmax, o, 64));
        float mn = fmaxf(m, cmax);
        float ex = (lane < len) ? __expf(myp - mn) : 0.f;
        float csum = ex;
#pragma unroll
        for (int o = 1; o < 64; o <<= 1) csum += __shfl_xor(csum, o, 64);
        float alpha = __expf(m - mn);
        s = s * alpha + csum;
        acc.x *= alpha; acc.y *= alpha; acc.z *= alpha; acc.w *= alpha;
        m = mn;
#pragma unroll 2
        for (int b = 0; b < nbatch; b++) {
            int eidx = b * SLOTS + slot;
            float w = __shfl(ex, eidx, 64);
            int src = __shfl(srcreg, eidx, 64);
            float4 v = *(const float4*)(xl + (size_t)src * C + c4);
            acc.x = fmaf(w, v.x, acc.x);
            acc.y = fmaf(w, v.y, acc.y);
            acc.z = fmaf(w, v.z, acc.z);
            acc.w = fmaf(w, v.w, acc.w);
        }
    }
#pragma unroll
    for (int o = LPQ; o < 64; o <<= 1) {
        acc.x += __shfl_xor(acc.x, o, 64);
        acc.y += __shfl_xor(acc.y, o, 64);
        acc.z += __shfl_xor(acc.z, o, 64);
        acc.w += __shfl_xor(acc.w, o, 64);
    }
    if (lane < LPQ) {
        float inv = 1.f / (s + 1e-16f);
        float4 o4;
        o4.x = acc.x * inv + bi4.x;
        o4.y = acc.y * inv + bi4.y;
        o4.z = acc.z * inv + bi4.z;
        o4.w = acc.w * inv + bi4.w;
        *(float4*)(out + (size_t)n * C + c4) = o4;
    }
}

extern "C" void kernel_launch(void* const* d_in, const int* in_sizes, int n_in,
                              void* d_out, int out_size, void* d_ws, size_t ws_size,
                              hipStream_t stream) {
    const float* x     = (const float*)d_in[0];
    const int*   ei    = (const int*)d_in[1];
    const float* W1l   = (const float*)d_in[2];
    const float* b1l   = (const float*)d_in[3];
    const float* W1r   = (const float*)d_in[4];
    const float* b1r   = (const float*)d_in[5];
    const float* att1  = (const float*)d_in[6];
    const float* bias1 = (const float*)d_in[7];
    const float* W2l   = (const float*)d_in[8];
    const float* b2l   = (const float*)d_in[9];
    const float* W2r   = (const float*)d_in[10];
    const float* b2r   = (const float*)d_in[11];
    const float* att2  = (const float*)d_in[12];
    const float* bias2 = (const float*)d_in[13];
    float* out = (float*)d_out;

    int N     = in_sizes[0] / F_IN;   // 100000
    int Eorig = in_sizes[1] / 2;      // 1600000
    int Etot  = Eorig + N;

    char* p = (char*)d_ws;
    auto alloc = [&](size_t bytes) { void* r = (void*)p; p += (bytes + 255) & ~(size_t)255; return r; };
    float* xl1     = (float*)alloc((size_t)N * HID * 4);
    float* xr1     = (float*)alloc((size_t)N * HID * 4);
    float* h       = (float*)alloc((size_t)N * HID * 4);
    float* xl2     = (float*)alloc((size_t)N * NCLS * 4);
    float* xr2     = (float*)alloc((size_t)N * NCLS * 4);
    int*   cnt     = (int*)alloc((size_t)N * 4);
    int*   cursor  = (int*)alloc((size_t)N * 4);
    int*   rowstart= (int*)alloc((size_t)N * 4);
    int*   srclist = (int*)alloc((size_t)Etot * 4);
    int*   bsum    = (int*)alloc(1024 * 4);

    int nb = (N + 1023) / 1024;
    int gridN = (N + 255) / 256;
    int gridE = (Etot + 255) / 256;

    // ---- CSR build (shared by both layers) ----
    zeroK<<<gridN, 256, 0, stream>>>(cnt, cursor, N);
    histK<<<gridE, 256, 0, stream>>>(ei, Eorig, Etot, cnt);
    scanLocal<<<nb, 256, 0, stream>>>(cnt, rowstart, bsum, N);
    scanBsum<<<1, 256, 0, stream>>>(bsum, nb);
    scanAdd<<<gridN, 256, 0, stream>>>(rowstart, bsum, N);
    scatterK<<<gridE, 256, 0, stream>>>(ei, Eorig, Etot, rowstart, cursor, srclist);

    // ---- layer 1 ----
    transform1<<<dim3((N + 63) / 64, 2), 256, 0, stream>>>(x, W1l, b1l, W1r, b1r,
                                                           xl1, xr1, N);
    fusedAggK<HID><<<(N + 3) / 4, 256, 0, stream>>>(xl1, xr1, att1, rowstart, cnt,
                                                    srclist, bias1, h, N);

    // ---- layer 2 ----
    transform2<<<(N + 127) / 128, 256, 0, stream>>>(h, W2l, b2l, W2r, b2r, xl2, xr2, N);
    fusedAggK<NCLS><<<(N + 3) / 4, 256, 0, stream>>>(xl2, xr2, att2, rowstart, cnt,
                                                     srclist, bias2, out, N);
}

// Round 7
// 409.237 us; speedup vs baseline: 3.7940x; 1.2743x over previous
//
#include <hip/hip_runtime.h>
#include <math.h>

#define F_IN 128
#define HID 64
#define NCLS 32
#define NEG 0.2f
#define NBKT 256          // nodes per bucket (dst >> 8)
#define CHUNK 8192        // edges per block in bucket passes

__device__ __forceinline__ void f4fma(float4& a, float s, const float4& w) {
    a.x = fmaf(s, w.x, a.x);
    a.y = fmaf(s, w.y, a.y);
    a.z = fmaf(s, w.z, a.z);
    a.w = fmaf(s, w.w, a.w);
}

// =====================  CSR build v2: bucketed counting sort  =====================

__global__ __launch_bounds__(256) void zeroBuckets(int* __restrict__ bucketSize, int BK) {
    int i = blockIdx.x * 256 + threadIdx.x;
    if (i < BK) bucketSize[i] = 0;
}

// K0: per-block LDS histogram of dst buckets -> few global atomics
__global__ __launch_bounds__(256) void bucketHist(const int* __restrict__ ei,
                                                  int Eorig, int Etot,
                                                  int* __restrict__ bucketSize, int BK) {
    __shared__ int h[512];
    int t = threadIdx.x;
    for (int j = t; j < BK; j += 256) h[j] = 0;
    __syncthreads();
    int base = blockIdx.x * CHUNK;
    int end = base + CHUNK < Etot ? base + CHUNK : Etot;
    for (int i = base + t; i < end; i += 256) {
        int dst = i < Eorig ? ei[Eorig + i] : i - Eorig;
        atomicAdd(&h[dst >> 8], 1);
    }
    __syncthreads();
    for (int j = t; j < BK; j += 256)
        if (h[j]) atomicAdd(&bucketSize[j], h[j]);
}

// K1: exclusive scan of bucket sizes (BK <= 512), single block
__global__ __launch_bounds__(256) void bucketScan(const int* __restrict__ bucketSize,
                                                  int* __restrict__ bucketStart,
                                                  int* __restrict__ bucketCursor,
                                                  int BK, int Etot) {
    __shared__ int sd[256];
    int t = threadIdx.x;
    int v0 = (2 * t     < BK) ? bucketSize[2 * t]     : 0;
    int v1 = (2 * t + 1 < BK) ? bucketSize[2 * t + 1] : 0;
    int ts = v0 + v1;
    sd[t] = ts;
    __syncthreads();
    for (int off = 1; off < 256; off <<= 1) {
        int x = (t >= off) ? sd[t - off] : 0;
        __syncthreads();
        sd[t] += x;
        __syncthreads();
    }
    int excl = sd[t] - ts;
    if (2 * t < BK)     { bucketStart[2 * t] = excl;          bucketCursor[2 * t] = excl; }
    if (2 * t + 1 < BK) { bucketStart[2 * t + 1] = excl + v0; bucketCursor[2 * t + 1] = excl + v0; }
    if (t == 255) bucketStart[BK] = Etot;
}

// K2: scatter (src,dst) pairs into bucket-contiguous runs (L2-friendly)
__global__ __launch_bounds__(256) void bucketScatter(const int* __restrict__ ei,
                                                     int Eorig, int Etot,
                                                     int* __restrict__ bucketCursor,
                                                     int2* __restrict__ pairs, int BK) {
    __shared__ int h[512], lbase[512], hcur[512];
    int t = threadIdx.x;
    for (int j = t; j < BK; j += 256) { h[j] = 0; hcur[j] = 0; }
    __syncthreads();
    int base = blockIdx.x * CHUNK;
    int end = base + CHUNK < Etot ? base + CHUNK : Etot;
    for (int i = base + t; i < end; i += 256) {
        int dst = i < Eorig ? ei[Eorig + i] : i - Eorig;
        atomicAdd(&h[dst >> 8], 1);
    }
    __syncthreads();
    for (int j = t; j < BK; j += 256)
        lbase[j] = h[j] ? atomicAdd(&bucketCursor[j], h[j]) : 0;
    __syncthreads();
    for (int i = base + t; i < end; i += 256) {
        int src, dst;
        if (i < Eorig) { src = ei[i]; dst = ei[Eorig + i]; }
        else           { src = dst = i - Eorig; }
        int b = dst >> 8;
        int off = atomicAdd(&hcur[b], 1);
        pairs[lbase[b] + off] = make_int2(src, dst);
    }
}

// K3: per-bucket fine CSR entirely in LDS (counts, scan, cursor)
__global__ __launch_bounds__(256) void bucketCSR(const int2* __restrict__ pairs,
                                                 const int* __restrict__ bucketStart,
                                                 int* __restrict__ rowstart,
                                                 int* __restrict__ cnt,
                                                 int* __restrict__ srclist, int N) {
    __shared__ int c[256], cur[256];
    int t = threadIdx.x;
    int b = blockIdx.x;
    int lo = b * NBKT;
    int eb = bucketStart[b], ee = bucketStart[b + 1];
    c[t] = 0;
    __syncthreads();
    for (int i = eb + t; i < ee; i += 256)
        atomicAdd(&c[pairs[i].y - lo], 1);
    __syncthreads();
    cur[t] = c[t];
    __syncthreads();
    for (int off = 1; off < 256; off <<= 1) {
        int x = (t >= off) ? cur[t - off] : 0;
        __syncthreads();
        cur[t] += x;
        __syncthreads();
    }
    int excl = cur[t] - c[t];
    int node = lo + t;
    if (node < N) { rowstart[node] = eb + excl; cnt[node] = c[t]; }
    __syncthreads();
    cur[t] = excl;
    __syncthreads();
    for (int i = eb + t; i < ee; i += 256) {
        int2 pr = pairs[i];
        int pos = atomicAdd(&cur[pr.y - lo], 1);
        srclist[eb + pos] = pr.x;
    }
}

// =====================  dense transforms (LDS-staged W)  =====================

__global__ __launch_bounds__(256) void transform1(const float* __restrict__ x,
                                                  const float* __restrict__ Wl,
                                                  const float* __restrict__ bl,
                                                  const float* __restrict__ Wr,
                                                  const float* __restrict__ br,
                                                  float* __restrict__ xl,
                                                  float* __restrict__ xr, int N) {
    __shared__ float sW[F_IN * HID];
    __shared__ float sx[64][132];
    const float* W = blockIdx.y ? Wr : Wl;
    const float* b = blockIdx.y ? br : bl;
    float* o       = blockIdx.y ? xr : xl;
    int t = threadIdx.x;
    int nb = blockIdx.x * 64;

#pragma unroll
    for (int j = 0; j < 8; j++) {
        int f = t + j * 256;
        ((float4*)sW)[f] = ((const float4*)W)[f];
    }
    int maxf = (N - nb) * 32;
#pragma unroll
    for (int j = 0; j < 8; j++) {
        int f = t + j * 256;
        int node = f >> 5, kc = f & 31;
        float4 v = {0.f, 0.f, 0.f, 0.f};
        if (f < maxf) v = ((const float4*)(x + (size_t)nb * F_IN))[f];
        *(float4*)&sx[node][kc * 4] = v;
    }
    __syncthreads();

    int c4 = (t & 15) * 4;
    int slot = t >> 4;
    float4 b4 = *(const float4*)(b + c4);
    float4 acc[4] = {b4, b4, b4, b4};

#pragma unroll 4
    for (int k4 = 0; k4 < F_IN / 4; k4++) {
        int k = k4 * 4;
        float4 w0 = *(const float4*)&sW[(k + 0) * HID + c4];
        float4 w1 = *(const float4*)&sW[(k + 1) * HID + c4];
        float4 w2 = *(const float4*)&sW[(k + 2) * HID + c4];
        float4 w3 = *(const float4*)&sW[(k + 3) * HID + c4];
#pragma unroll
        for (int j = 0; j < 4; j++) {
            float4 xv = *(const float4*)&sx[slot + j * 16][k];
            f4fma(acc[j], xv.x, w0);
            f4fma(acc[j], xv.y, w1);
            f4fma(acc[j], xv.z, w2);
            f4fma(acc[j], xv.w, w3);
        }
    }
#pragma unroll
    for (int j = 0; j < 4; j++) {
        int g = nb + slot + j * 16;
        if (g < N) *(float4*)(o + (size_t)g * HID + c4) = acc[j];
    }
}

__global__ __launch_bounds__(256) void transform2(const float* __restrict__ h,
                                                  const float* __restrict__ Wl,
                                                  const float* __restrict__ bl,
                                                  const float* __restrict__ Wr,
                                                  const float* __restrict__ br,
                                                  float* __restrict__ xl,
                                                  float* __restrict__ xr, int N) {
    __shared__ float sWl[HID * NCLS];
    __shared__ float sWr[HID * NCLS];
    __shared__ float sx[128][68];
    int t = threadIdx.x;
    int nb = blockIdx.x * 128;

#pragma unroll
    for (int j = 0; j < 2; j++) {
        int f = t + j * 256;
        ((float4*)sWl)[f] = ((const float4*)Wl)[f];
        ((float4*)sWr)[f] = ((const float4*)Wr)[f];
    }
    int maxf = (N - nb) * 16;
#pragma unroll
    for (int j = 0; j < 8; j++) {
        int f = t + j * 256;
        int node = f >> 4, kc = f & 15;
        float4 v = {0.f, 0.f, 0.f, 0.f};
        if (f < maxf) v = ((const float4*)(h + (size_t)nb * HID))[f];
        v.x = fmaxf(v.x, 0.f);
        v.y = fmaxf(v.y, 0.f);
        v.z = fmaxf(v.z, 0.f);
        v.w = fmaxf(v.w, 0.f);
        *(float4*)&sx[node][kc * 4] = v;
    }
    __syncthreads();

    int c4 = (t & 7) * 4;
    int slot = t >> 3;
    float4 bl4 = *(const float4*)(bl + c4);
    float4 br4 = *(const float4*)(br + c4);
    float4 accl[4] = {bl4, bl4, bl4, bl4};
    float4 accr[4] = {br4, br4, br4, br4};

#pragma unroll 4
    for (int k4 = 0; k4 < HID / 4; k4++) {
        int k = k4 * 4;
        float4 wl0 = *(const float4*)&sWl[(k + 0) * NCLS + c4];
        float4 wl1 = *(const float4*)&sWl[(k + 1) * NCLS + c4];
        float4 wl2 = *(const float4*)&sWl[(k + 2) * NCLS + c4];
        float4 wl3 = *(const float4*)&sWl[(k + 3) * NCLS + c4];
        float4 wr0 = *(const float4*)&sWr[(k + 0) * NCLS + c4];
        float4 wr1 = *(const float4*)&sWr[(k + 1) * NCLS + c4];
        float4 wr2 = *(const float4*)&sWr[(k + 2) * NCLS + c4];
        float4 wr3 = *(const float4*)&sWr[(k + 3) * NCLS + c4];
#pragma unroll
        for (int j = 0; j < 4; j++) {
            float4 xv = *(const float4*)&sx[slot + j * 32][k];
            f4fma(accl[j], xv.x, wl0); f4fma(accr[j], xv.x, wr0);
            f4fma(accl[j], xv.y, wl1); f4fma(accr[j], xv.y, wr1);
            f4fma(accl[j], xv.z, wl2); f4fma(accr[j], xv.z, wr2);
            f4fma(accl[j], xv.w, wl3); f4fma(accr[j], xv.w, wr3);
        }
    }
#pragma unroll
    for (int j = 0; j < 4; j++) {
        int g = nb + slot + j * 32;
        if (g < N) {
            *(float4*)(xl + (size_t)g * NCLS + c4) = accl[j];
            *(float4*)(xr + (size_t)g * NCLS + c4) = accr[j];
        }
    }
}

// =====================  fused softmax aggregation (unchanged)  =====================
template <int C>
__global__ __launch_bounds__(256) void fusedAggK(const float* __restrict__ xl,
                                                 const float* __restrict__ xr,
                                                 const float* __restrict__ att,
                                                 const int* __restrict__ rowstart,
                                                 const int* __restrict__ cnt,
                                                 const int* __restrict__ srclist,
                                                 const float* __restrict__ bias,
                                                 float* __restrict__ out, int N) {
    const int LPQ = C / 4;
    const int SLOTS = 64 / LPQ;
    int wid = threadIdx.x >> 6;
    int lane = threadIdx.x & 63;
    int n = blockIdx.x * 4 + wid;
    if (n >= N) return;

    int slot = lane / LPQ;
    int pos = lane % LPQ;
    int c4 = pos * 4;

    float4 xr4 = *(const float4*)(xr + (size_t)n * C + c4);
    float4 at4 = *(const float4*)(att + c4);
    float4 bi4 = *(const float4*)(bias + c4);

    int row = rowstart[n];
    int deg = cnt[n];

    float m = -INFINITY, s = 0.f;
    float4 acc = {0.f, 0.f, 0.f, 0.f};

    for (int cb = 0; cb < deg; cb += 64) {
        int len = deg - cb; if (len > 64) len = 64;
        int li = lane < len ? lane : len - 1;
        int srcreg = srclist[row + cb + li];

        int nbatch = (len + SLOTS - 1) / SLOTS;
        float myp = 0.f;
#pragma unroll 2
        for (int b = 0; b < nbatch; b++) {
            int eidx = b * SLOTS + slot;
            int src = __shfl(srcreg, eidx, 64);
            float4 v = *(const float4*)(xl + (size_t)src * C + c4);
            v.x += xr4.x; v.y += xr4.y; v.z += xr4.z; v.w += xr4.w;
            v.x = fmaxf(v.x, NEG * v.x);
            v.y = fmaxf(v.y, NEG * v.y);
            v.z = fmaxf(v.z, NEG * v.z);
            v.w = fmaxf(v.w, NEG * v.w);
            float p = v.x * at4.x;
            p = fmaf(v.y, at4.y, p);
            p = fmaf(v.z, at4.z, p);
            p = fmaf(v.w, at4.w, p);
#pragma unroll
            for (int o = 1; o < LPQ; o <<= 1) p += __shfl_xor(p, o, 64);
            float got = __shfl(p, (lane & (SLOTS - 1)) * LPQ, 64);
            myp = (b == lane / SLOTS) ? got : myp;
        }
        float pv = (lane < len) ? myp : -INFINITY;
        float cmax = pv;
#pragma unroll
        for (int o = 1; o < 64; o <<= 1) cmax = fmaxf(cmax, __shfl_xor(cmax, o, 64));
        float mn = fmaxf(m, cmax);
        float ex = (lane < len) ? __expf(myp - mn) : 0.f;
        float csum = ex;
#pragma unroll
        for (int o = 1; o < 64; o <<= 1) csum += __shfl_xor(csum, o, 64);
        float alpha = __expf(m - mn);
        s = s * alpha + csum;
        acc.x *= alpha; acc.y *= alpha; acc.z *= alpha; acc.w *= alpha;
        m = mn;
#pragma unroll 2
        for (int b = 0; b < nbatch; b++) {
            int eidx = b * SLOTS + slot;
            float w = __shfl(ex, eidx, 64);
            int src = __shfl(srcreg, eidx, 64);
            float4 v = *(const float4*)(xl + (size_t)src * C + c4);
            acc.x = fmaf(w, v.x, acc.x);
            acc.y = fmaf(w, v.y, acc.y);
            acc.z = fmaf(w, v.z, acc.z);
            acc.w = fmaf(w, v.w, acc.w);
        }
    }
#pragma unroll
    for (int o = LPQ; o < 64; o <<= 1) {
        acc.x += __shfl_xor(acc.x, o, 64);
        acc.y += __shfl_xor(acc.y, o, 64);
        acc.z += __shfl_xor(acc.z, o, 64);
        acc.w += __shfl_xor(acc.w, o, 64);
    }
    if (lane < LPQ) {
        float inv = 1.f / (s + 1e-16f);
        float4 o4;
        o4.x = acc.x * inv + bi4.x;
        o4.y = acc.y * inv + bi4.y;
        o4.z = acc.z * inv + bi4.z;
        o4.w = acc.w * inv + bi4.w;
        *(float4*)(out + (size_t)n * C + c4) = o4;
    }
}

extern "C" void kernel_launch(void* const* d_in, const int* in_sizes, int n_in,
                              void* d_out, int out_size, void* d_ws, size_t ws_size,
                              hipStream_t stream) {
    const float* x     = (const float*)d_in[0];
    const int*   ei    = (const int*)d_in[1];
    const float* W1l   = (const float*)d_in[2];
    const float* b1l   = (const float*)d_in[3];
    const float* W1r   = (const float*)d_in[4];
    const float* b1r   = (const float*)d_in[5];
    const float* att1  = (const float*)d_in[6];
    const float* bias1 = (const float*)d_in[7];
    const float* W2l   = (const float*)d_in[8];
    const float* b2l   = (const float*)d_in[9];
    const float* W2r   = (const float*)d_in[10];
    const float* b2r   = (const float*)d_in[11];
    const float* att2  = (const float*)d_in[12];
    const float* bias2 = (const float*)d_in[13];
    float* out = (float*)d_out;

    int N     = in_sizes[0] / F_IN;   // 100000
    int Eorig = in_sizes[1] / 2;      // 1600000
    int Etot  = Eorig + N;
    int BK    = (N + NBKT - 1) / NBKT;   // 391 buckets (<=512)

    char* p = (char*)d_ws;
    auto alloc = [&](size_t bytes) { void* r = (void*)p; p += (bytes + 255) & ~(size_t)255; return r; };
    float* xl1     = (float*)alloc((size_t)N * HID * 4);
    float* xr1     = (float*)alloc((size_t)N * HID * 4);
    float* h       = (float*)alloc((size_t)N * HID * 4);
    float* xl2     = (float*)alloc((size_t)N * NCLS * 4);
    float* xr2     = (float*)alloc((size_t)N * NCLS * 4);
    int*   cnt     = (int*)alloc((size_t)N * 4);
    int*   rowstart= (int*)alloc((size_t)N * 4);
    int*   srclist = (int*)alloc((size_t)Etot * 4);
    int*   bucketSize   = (int*)alloc(520 * 4);
    int*   bucketStart  = (int*)alloc(520 * 4);
    int*   bucketCursor = (int*)alloc(520 * 4);
    // pairs (Etot int2 = 13.6MB) aliased onto xl2+xr2 (25.6MB, dead during CSR build)
    int2*  pairs   = (int2*)xl2;

    int nChunks = (Etot + CHUNK - 1) / CHUNK;

    // ---- CSR build (bucketed counting sort) ----
    zeroBuckets<<<2, 256, 0, stream>>>(bucketSize, BK);
    bucketHist<<<nChunks, 256, 0, stream>>>(ei, Eorig, Etot, bucketSize, BK);
    bucketScan<<<1, 256, 0, stream>>>(bucketSize, bucketStart, bucketCursor, BK, Etot);
    bucketScatter<<<nChunks, 256, 0, stream>>>(ei, Eorig, Etot, bucketCursor, pairs, BK);
    bucketCSR<<<BK, 256, 0, stream>>>(pairs, bucketStart, rowstart, cnt, srclist, N);

    // ---- layer 1 ----
    transform1<<<dim3((N + 63) / 64, 2), 256, 0, stream>>>(x, W1l, b1l, W1r, b1r,
                                                           xl1, xr1, N);
    fusedAggK<HID><<<(N + 3) / 4, 256, 0, stream>>>(xl1, xr1, att1, rowstart, cnt,
                                                    srclist, bias1, h, N);

    // ---- layer 2 ----
    transform2<<<(N + 127) / 128, 256, 0, stream>>>(h, W2l, b2l, W2r, b2r, xl2, xr2, N);
    fusedAggK<NCLS><<<(N + 3) / 4, 256, 0, stream>>>(xl2, xr2, att2, rowstart, cnt,
                                                     srclist, bias2, out, N);
}